// Round 1
// baseline (637.683 us; speedup 1.0000x reference)
//
#include <hip/hip_runtime.h>

// ExtractTensorPatches: x (8,32,256,256) f32, 3x3 window, stride 1, pad 1.
// out[bc][k][ho][wo] = x[bc, ho+ki-1, wo+kj-1] (zero-padded), k = ki*3+kj.
//
// Rolling-register structure: each wave owns (bc, 8-row strip). A wave's 64
// lanes x float4 = 256 cover one full row. Rows are loaded ONCE into a
// rolling 3-deep register pipeline (A=ho-1, B=ho, C=ho+1); the +/-1 w-shifts
// (wave-edge == pad 0) are computed once per LOADED row (2 shuffles) and
// reused by all 3 ki consumers. Per output row: 1.125 loads, 2.5 shuffles,
// 9 coalesced dwordx4 stores; each k-stream is an 8 KB sequential run per
// wave (32 KB per block) instead of a lone 1 KB burst.
// Traffic: ~72 MB read + 604 MB write => ~107 us floor @ 6.3 TB/s.

#define BDIM 256
#define ROWS 8   // output rows per wave; 2048 blocks, 8192 waves = 32/CU

typedef float vf4 __attribute__((ext_vector_type(4)));

__device__ __forceinline__ vf4 load_row(const float* __restrict__ img,
                                        int hi, int lane) {
    vf4 r = {0.f, 0.f, 0.f, 0.f};
    if ((unsigned)hi < 256u) {  // wave-uniform (hi doesn't depend on lane)
        r = *reinterpret_cast<const vf4*>(img + (hi << 8) + (lane << 2));
    }
    return r;
}

__device__ __forceinline__ void shifts(vf4 r, int lane, vf4& L, vf4& R) {
    float lw = __shfl_up(r.w, 1, 64);    // x[wo-1] for element 0
    float rx = __shfl_down(r.x, 1, 64);  // x[wo+4] for element 3
    if (lane == 0)  lw = 0.f;            // wave edge == image edge == pad 0
    if (lane == 63) rx = 0.f;
    L = {lw,  r.x, r.y, r.z};            // kj = 0: x[.., wo-1 .. wo+2]
    R = {r.y, r.z, r.w, rx};             // kj = 2: x[.., wo+1 .. wo+4]
}

__global__ __launch_bounds__(BDIM) void extract_patches_kernel(
    const float* __restrict__ x, float* __restrict__ out)
{
    int lane = threadIdx.x & 63;
    int wave = threadIdx.x >> 6;
    int bc   = blockIdx.x >> 3;                  // 8 blocks per bc
    int rg   = ((blockIdx.x & 7) << 2) | wave;   // rowgroup 0..31
    int row0 = rg << 3;                          // first output row of strip

    const float* img = x + ((size_t)bc << 16);
    float* ob = out + ((size_t)(bc * 9) << 16) + (lane << 2);

    // Prime the pipeline: A = row(row0-1), B = row(row0)
    vf4 A = load_row(img, row0 - 1, lane);
    vf4 B = load_row(img, row0,     lane);
    vf4 LA, RA, LB, RB;
    shifts(A, lane, LA, RA);
    shifts(B, lane, LB, RB);

#pragma unroll
    for (int r = 0; r < ROWS; ++r) {
        int ho = row0 + r;
        vf4 C = load_row(img, ho + 1, lane);     // bottom row of this window
        vf4 LC, RC;
        shifts(C, lane, LC, RC);

        float* o = ob + (ho << 8);
        // k = ki*3 + kj; ki=0 -> row ho-1 (A), ki=1 -> B, ki=2 -> C
        *reinterpret_cast<vf4*>(o)              = LA;
        *reinterpret_cast<vf4*>(o + 1 * 65536)  = A;
        *reinterpret_cast<vf4*>(o + 2 * 65536)  = RA;
        *reinterpret_cast<vf4*>(o + 3 * 65536)  = LB;
        *reinterpret_cast<vf4*>(o + 4 * 65536)  = B;
        *reinterpret_cast<vf4*>(o + 5 * 65536)  = RB;
        *reinterpret_cast<vf4*>(o + 6 * 65536)  = LC;
        *reinterpret_cast<vf4*>(o + 7 * 65536)  = C;
        *reinterpret_cast<vf4*>(o + 8 * 65536)  = RC;

        // rotate (SSA renames after full unroll — no register copies)
        A = B; LA = LB; RA = RB;
        B = C; LB = LC; RB = RC;
    }
}

extern "C" void kernel_launch(void* const* d_in, const int* in_sizes, int n_in,
                              void* d_out, int out_size, void* d_ws, size_t ws_size,
                              hipStream_t stream) {
    const float* x = (const float*)d_in[0];
    float* out = (float*)d_out;
    // waves = 256 bc * 32 rowgroups = 8192; 4 waves/block -> 2048 blocks
    int grid = 256 * 8;
    extract_patches_kernel<<<grid, BDIM, 0, stream>>>(x, out);
}